// Round 13
// baseline (6920.499 us; speedup 1.0000x reference)
//
#include <hip/hip_runtime.h>
#include <math.h>

#define NN 50000
#define NE 600000
#define HD 128
#define NL 10
#define LN_EPS 1e-5f
#define SCAN_B 256
#define NBLK ((NN + SCAN_B - 1) / SCAN_B)   // 196

typedef unsigned short ushort_t;
typedef __attribute__((ext_vector_type(8))) short bf16x8;
typedef __attribute__((ext_vector_type(4))) float f32x4;

// fast GELU: x*sigmoid(1.5957691*(x+0.044715*x^3)); |err| vs erf-GELU ~1e-3
__device__ __forceinline__ float gelu_f(float x){
    float x2 = x*x;
    float z  = 1.5957691f*x + 0.07135481f*x2*x;
    float s  = 1.0f/(1.0f + __expf(-z));
    return x*s;
}
__device__ __forceinline__ float bf2f(ushort_t u){
    unsigned int x = ((unsigned int)u) << 16;
    float f; __builtin_memcpy(&f, &x, 4); return f;
}
__device__ __forceinline__ ushort_t f2bf(float f){
    unsigned int x; __builtin_memcpy(&x, &f, 4);
    unsigned int lsb = (x >> 16) & 1u;
    x += 0x7fffu + lsb;                 // round-to-nearest-even
    return (ushort_t)(x >> 16);
}

// ---------------- sentinel fill (ws-too-small diagnostic) ----------------
__global__ void k_sentinel_out(float* __restrict__ out, int n, float v){
    int i = blockIdx.x*256 + threadIdx.x;
    if (i < n) out[i] = v;
}

// ---------------- weight pre-transpose+convert: WT[l][n][k] = bf16(W[l][k][n]) ----------------
__global__ void k_wt(const float* __restrict__ W, ushort_t* __restrict__ WT, int K, int N){
    int idx = blockIdx.x*256 + threadIdx.x;
    if (idx >= NL*K*N) return;
    int l = idx / (K*N);
    int rem = idx - l*(K*N);
    int n = rem / K;
    int k = rem - n*K;
    WT[idx] = f2bf(W[(size_t)l*K*N + (size_t)k*N + n]);
}

// ---------------- encoder: h = gelu(LN(x @ W + b)); writes f32 + bf16 mirror ----------------
__global__ __launch_bounds__(128) void k_encode_nodes(
    const float* __restrict__ x, const float* __restrict__ W,
    const float* __restrict__ b, const float* __restrict__ g,
    const float* __restrict__ beta, float* __restrict__ h, ushort_t* __restrict__ h_bf)
{
    int n = blockIdx.x;
    int t = threadIdx.x;
    __shared__ float xs[7];
    __shared__ float red[4];
    if (t < 7) xs[t] = x[n*7 + t];
    __syncthreads();
    float acc = b[t];
    #pragma unroll
    for (int i = 0; i < 7; ++i) acc += xs[i] * W[i*HD + t];
    float s = acc, s2 = acc*acc;
    #pragma unroll
    for (int m = 32; m >= 1; m >>= 1) { s += __shfl_xor(s, m); s2 += __shfl_xor(s2, m); }
    int wave = t >> 6;
    if ((t & 63) == 0) { red[wave*2] = s; red[wave*2+1] = s2; }
    __syncthreads();
    s = red[0] + red[2]; s2 = red[1] + red[3];
    float mean = s * (1.0f/HD);
    float var  = s2 * (1.0f/HD) - mean*mean;
    float rs = rsqrtf(var + LN_EPS);
    float v = (acc - mean) * rs * g[t] + beta[t];
    float o = gelu_f(v);
    h[(size_t)n*HD + t] = o;
    h_bf[(size_t)n*HD + t] = f2bf(o);
}

// ---------------- edge encoder: ea = attr @ W + b (bf16 store) ----------------
__global__ __launch_bounds__(256) void k_encode_edges(
    const float* __restrict__ attr, const float* __restrict__ W,
    const float* __restrict__ b, ushort_t* __restrict__ ea)
{
    int e = blockIdx.x * 2 + (threadIdx.x >> 7);
    int c = threadIdx.x & 127;
    float acc = b[c];
    #pragma unroll
    for (int i = 0; i < 8; ++i) acc += attr[(size_t)e*8 + i] * W[i*HD + c];
    ea[(size_t)e*HD + c] = f2bf(acc);
}

// ---------------- CSR build ----------------
__global__ void k_hist(const int* __restrict__ col, int* __restrict__ cnt){
    int e = blockIdx.x*256 + threadIdx.x;
    if (e < NE) atomicAdd(&cnt[col[e]], 1);
}

__global__ __launch_bounds__(256) void k_scan1(const int* __restrict__ cnt, int* __restrict__ bsum){
    __shared__ int s[256];
    int i = blockIdx.x*256 + threadIdx.x;
    int t = threadIdx.x;
    s[t] = (i < NN) ? cnt[i] : 0;
    __syncthreads();
    for (int off = 128; off >= 1; off >>= 1){
        if (t < off) s[t] += s[t+off];
        __syncthreads();
    }
    if (t == 0) bsum[blockIdx.x] = s[0];
}

__global__ __launch_bounds__(256) void k_scan2(const int* __restrict__ bsum, int* __restrict__ boff){
    __shared__ int s[256];
    int t = threadIdx.x;
    int v = (t < NBLK) ? bsum[t] : 0;
    s[t] = v; __syncthreads();
    for (int off = 1; off < 256; off <<= 1){
        int tmp = (t >= off) ? s[t-off] : 0;
        __syncthreads();
        s[t] += tmp;
        __syncthreads();
    }
    if (t < NBLK) boff[t] = s[t] - v;   // exclusive
}

__global__ __launch_bounds__(256) void k_scan3(const int* __restrict__ cnt, const int* __restrict__ boff,
        int* __restrict__ rowStart, float* __restrict__ invcnt){
    __shared__ int s[256];
    int i = blockIdx.x*256 + threadIdx.x;
    int t = threadIdx.x;
    int v = (i < NN) ? cnt[i] : 0;
    s[t] = v; __syncthreads();
    for (int off = 1; off < 256; off <<= 1){
        int tmp = (t >= off) ? s[t-off] : 0;
        __syncthreads();
        s[t] += tmp;
        __syncthreads();
    }
    if (i < NN){
        rowStart[i] = boff[blockIdx.x] + s[t] - v;
        invcnt[i]   = 1.0f / fmaxf((float)v, 1.0f);
    }
}

__global__ void k_fill(const int* __restrict__ col, const int* __restrict__ rowStart,
                       int* __restrict__ fill, int* __restrict__ edgeIds){
    int e = blockIdx.x*256 + threadIdx.x;
    if (e < NE){
        int c = col[e];
        int p = rowStart[c] + atomicAdd(&fill[c], 1);
        edgeIds[p] = e;
    }
}

// ---------------- MFMA fused edge update (64 edges/block, 4 waves, A+B reg-pipelined) ----------------
// Fragment maps: A: row=lane&15 (+16*rt), k=(lane>>4)*8+j.  B: col=lane&15, k=(lane>>4)*8+j.
// C/D: col=lane&15, row=(lane>>4)*4+reg (HW-verified).
#define EB 64    // edges per block
#define AP 392   // A LDS row stride (shorts)
#define A2P 264  // A2 row stride (shorts)
__global__ __launch_bounds__(256) void k_edge_update(
    const ushort_t* __restrict__ h_bf, ushort_t* __restrict__ ea,
    const int* __restrict__ row, const int* __restrict__ col,
    const ushort_t* __restrict__ W1T, const float* __restrict__ b1,
    const float* __restrict__ g1, const float* __restrict__ bt1,
    const ushort_t* __restrict__ W2T, const float* __restrict__ b2,
    const float* __restrict__ g2, const float* __restrict__ bt2)
{
    __shared__ short As[EB*AP];          // 50176 B; aliased as A2s after phase 1
    __shared__ float red[4][EB][2];      // 2 KB cross-wave LN partials

    const int tid  = threadIdx.x;
    const int lane = tid & 63;
    const int w    = tid >> 6;           // wave 0..3
    const int l15  = lane & 15;
    const int lg   = lane >> 4;          // 0..3
    const int eBase = blockIdx.x * EB;

    // ---- B phase-1 prefetch ring (depth 4): issued FIRST so L2 latency hides under staging ----
    bf16x8 bf[4][4];
    #pragma unroll
    for (int p = 0; p < 4; ++p)
        #pragma unroll
        for (int c = 0; c < 4; ++c)
            bf[p][c] = *(const bf16x8*)&W1T[(size_t)(w*64 + c*16 + l15)*384 + p*32 + lg*8];

    // ---- stage A tile: raw bf16 uint4 copies (64 edges x 16 uint4 per segment) ----
    #pragma unroll
    for (int it = 0; it < 4; ++it){
        int f = tid + it*256;            // 0..1023
        int e = f >> 4, q = f & 15;
        int rn = row[eBase + e];         // 16 threads share e -> broadcast load
        uint4 v = *(const uint4*)(h_bf + (size_t)rn*HD + q*8);
        *(uint4*)&As[e*AP + q*8] = v;
    }
    #pragma unroll
    for (int it = 0; it < 4; ++it){
        int f = tid + it*256;
        int e = f >> 4, q = f & 15;
        int cn = col[eBase + e];
        uint4 v = *(const uint4*)(h_bf + (size_t)cn*HD + q*8);
        *(uint4*)&As[e*AP + 128 + q*8] = v;
    }
    #pragma unroll
    for (int it = 0; it < 4; ++it){
        int f = tid + it*256;
        int e = f >> 4, q = f & 15;
        uint4 v = *(const uint4*)(ea + (size_t)(eBase+e)*HD + q*8);
        *(uint4*)&As[e*AP + 256 + q*8] = v;
    }
    __syncthreads();

    // ---- phase 1: (64x384)@(384x256); A double-buffered in regs, B prefetched 4 deep ----
    f32x4 acc[4][4];
    #pragma unroll
    for (int rt=0;rt<4;++rt)
        #pragma unroll
        for (int c=0;c<4;++c) acc[rt][c] = (f32x4){0.f,0.f,0.f,0.f};

    bf16x8 a[2][4];
    #pragma unroll
    for (int rt=0;rt<4;++rt) a[0][rt] = *(const bf16x8*)&As[(l15 + 16*rt)*AP + lg*8];

    #pragma unroll
    for (int kc = 0; kc < 12; ++kc){
        if (kc < 11){
            int k0n = (kc+1)*32 + lg*8;
            #pragma unroll
            for (int rt=0;rt<4;++rt)
                a[(kc+1)&1][rt] = *(const bf16x8*)&As[(l15 + 16*rt)*AP + k0n];
        }
        #pragma unroll
        for (int c=0;c<4;++c){
            #pragma unroll
            for (int rt=0;rt<4;++rt)
                acc[rt][c] = __builtin_amdgcn_mfma_f32_16x16x32_bf16(a[kc&1][rt], bf[kc&3][c], acc[rt][c], 0, 0, 0);
        }
        if (kc < 8){
            #pragma unroll
            for (int c=0;c<4;++c)
                bf[kc&3][c] = *(const bf16x8*)&W1T[(size_t)(w*64 + c*16 + l15)*384 + (kc+4)*32 + lg*8];
        }
    }

    // ---- epilogue 1: +b1, LN(256), GELU -> A2s (bf16) ----
    float b1c[4], g1c[4], t1c[4];
    #pragma unroll
    for (int c=0;c<4;++c){
        int colg = w*64 + c*16 + l15;
        b1c[c] = b1[colg]; g1c[c] = g1[colg]; t1c[c] = bt1[colg];
    }
    float xv[4][4][4];
    #pragma unroll
    for (int rt=0;rt<4;++rt)
        #pragma unroll
        for (int c=0;c<4;++c)
            #pragma unroll
            for (int i=0;i<4;++i) xv[rt][c][i] = acc[rt][c][i] + b1c[c];

    #pragma unroll
    for (int rt=0;rt<4;++rt)
        #pragma unroll
        for (int i=0;i<4;++i){
            float s=0.f, q=0.f;
            #pragma unroll
            for (int c=0;c<4;++c){ float v=xv[rt][c][i]; s+=v; q+=v*v; }
            #pragma unroll
            for (int m=1;m<16;m<<=1){ s += __shfl_xor(s,m); q += __shfl_xor(q,m); }
            if (l15 == 0){
                int r = rt*16 + lg*4 + i;
                red[w][r][0] = s;
                red[w][r][1] = q;
            }
        }
    __syncthreads();   // red ready; also all phase-1 LDS reads done before A2s overwrite

    // ---- B phase-2 prefetch ring: issued here so latency hides under epilogue-1 VALU ----
    bf16x8 bf2[4][2];
    #pragma unroll
    for (int p = 0; p < 4; ++p)
        #pragma unroll
        for (int c = 0; c < 2; ++c)
            bf2[p][c] = *(const bf16x8*)&W2T[(size_t)(w*32 + c*16 + l15)*256 + p*32 + lg*8];

    short* A2s = &As[0];
    #pragma unroll
    for (int rt=0;rt<4;++rt)
        #pragma unroll
        for (int i=0;i<4;++i){
            int r = rt*16 + lg*4 + i;
            float S = red[0][r][0]+red[1][r][0]+red[2][r][0]+red[3][r][0];
            float Q = red[0][r][1]+red[1][r][1]+red[2][r][1]+red[3][r][1];
            float mean = S * (1.f/256.f);
            float var  = Q * (1.f/256.f) - mean*mean;
            float rs = rsqrtf(var + LN_EPS);
            #pragma unroll
            for (int c=0;c<4;++c){
                int colg = w*64 + c*16 + l15;
                float v = (xv[rt][c][i]-mean)*rs*g1c[c] + t1c[c];
                A2s[r*A2P + colg] = (short)f2bf(gelu_f(v));
            }
        }
    __syncthreads();

    // ---- phase 2: (64x256)@(256x128); A double-buffered in regs ----
    f32x4 acc2[4][2];
    #pragma unroll
    for (int rt=0;rt<4;++rt)
        #pragma unroll
        for (int c=0;c<2;++c) acc2[rt][c] = (f32x4){0.f,0.f,0.f,0.f};

    bf16x8 a2[2][4];
    #pragma unroll
    for (int rt=0;rt<4;++rt) a2[0][rt] = *(const bf16x8*)&A2s[(l15 + 16*rt)*A2P + lg*8];

    #pragma unroll
    for (int kc = 0; kc < 8; ++kc){
        if (kc < 7){
            int k0n = (kc+1)*32 + lg*8;
            #pragma unroll
            for (int rt=0;rt<4;++rt)
                a2[(kc+1)&1][rt] = *(const bf16x8*)&A2s[(l15 + 16*rt)*A2P + k0n];
        }
        #pragma unroll
        for (int c=0;c<2;++c){
            #pragma unroll
            for (int rt=0;rt<4;++rt)
                acc2[rt][c] = __builtin_amdgcn_mfma_f32_16x16x32_bf16(a2[kc&1][rt], bf2[kc&3][c], acc2[rt][c], 0, 0, 0);
        }
        if (kc < 4){
            #pragma unroll
            for (int c=0;c<2;++c)
                bf2[kc&3][c] = *(const bf16x8*)&W2T[(size_t)(w*32 + c*16 + l15)*256 + (kc+4)*32 + lg*8];
        }
    }

    // ---- epilogue 2: +b2, LN(128), residual into ea (bf16) ----
    float b2c[2], g2c[2], t2c[2];
    #pragma unroll
    for (int c=0;c<2;++c){
        int colg = w*32 + c*16 + l15;
        b2c[c] = b2[colg]; g2c[c] = g2[colg]; t2c[c] = bt2[colg];
    }
    float yv[4][2][4];
    #pragma unroll
    for (int rt=0;rt<4;++rt)
        #pragma unroll
        for (int c=0;c<2;++c)
            #pragma unroll
            for (int i=0;i<4;++i) yv[rt][c][i] = acc2[rt][c][i] + b2c[c];

    __syncthreads();   // ensure epi-1 red reads done before reuse
    #pragma unroll
    for (int rt=0;rt<4;++rt)
        #pragma unroll
        for (int i=0;i<4;++i){
            float s=0.f, q=0.f;
            #pragma unroll
            for (int c=0;c<2;++c){ float v=yv[rt][c][i]; s+=v; q+=v*v; }
            #pragma unroll
            for (int m=1;m<16;m<<=1){ s += __shfl_xor(s,m); q += __shfl_xor(q,m); }
            if (l15 == 0){
                int r = rt*16 + lg*4 + i;
                red[w][r][0] = s;
                red[w][r][1] = q;
            }
        }
    __syncthreads();

    #pragma unroll
    for (int rt=0;rt<4;++rt)
        #pragma unroll
        for (int i=0;i<4;++i){
            int r = rt*16 + lg*4 + i;
            float S = red[0][r][0]+red[1][r][0]+red[2][r][0]+red[3][r][0];
            float Q = red[0][r][1]+red[1][r][1]+red[2][r][1]+red[3][r][1];
            float mean = S * (1.f/128.f);
            float var  = Q * (1.f/128.f) - mean*mean;
            float rs = rsqrtf(var + LN_EPS);
            size_t gbase = (size_t)(eBase + r)*HD;
            #pragma unroll
            for (int c=0;c<2;++c){
                int colg = w*32 + c*16 + l15;
                float v = (yv[rt][c][i]-mean)*rs*g2c[c] + t2c[c];
                float old = bf2f(ea[gbase + colg]);
                ea[gbase + colg] = f2bf(old + v);
            }
        }
}

// ---------------- MFMA fused node update (agg fused in, gather unrolled x4) ----------------
#define NP 264   // LDS row stride (shorts) for 256-col tiles
__global__ __launch_bounds__(256) void k_node_update(
    float* __restrict__ h, ushort_t* __restrict__ h_bf,
    const ushort_t* __restrict__ ea,
    const int* __restrict__ rowSt, const int* __restrict__ cnt,
    const float* __restrict__ invcnt, const int* __restrict__ edgeIds,
    const ushort_t* __restrict__ W1T, const float* __restrict__ b1,
    const float* __restrict__ g1, const float* __restrict__ bt1,
    const ushort_t* __restrict__ W2T, const float* __restrict__ b2,
    const float* __restrict__ g2, const float* __restrict__ bt2)
{
    __shared__ short As[32*NP];          // 16896 B; reused as A2s after phase 1
    __shared__ float red[4][32][2];

    const int tid  = threadIdx.x;
    const int lane = tid & 63;
    const int w    = tid >> 6;
    const int l15  = lane & 15;
    const int lg   = lane >> 4;
    const int nBase = blockIdx.x * 32;

    // ---- stage h_bf rows (cols 0..127) ----
    #pragma unroll
    for (int it = 0; it < 2; ++it){
        int f = tid + it*256;            // 0..511
        int e = f >> 4, q = f & 15;
        int gn = nBase + e;
        uint4 v = make_uint4(0,0,0,0);
        if (gn < NN) v = *(const uint4*)(h_bf + (size_t)gn*HD + q*8);
        *(uint4*)&As[e*NP + q*8] = v;
    }
    // ---- CSR gather-mean into cols 128..255 (bf16), 4-way unrolled ----
    {
        const int cg  = tid & 127;
        const int grp = tid >> 7;
        for (int i = 0; i < 16; ++i){
            int ln = grp*16 + i;
            int gn = nBase + ln;
            float s = 0.f;
            if (gn < NN){
                int st = rowSt[gn], dg = cnt[gn];
                int j = 0;
                for (; j + 4 <= dg; j += 4){
                    int e0 = edgeIds[st+j+0];
                    int e1 = edgeIds[st+j+1];
                    int e2 = edgeIds[st+j+2];
                    int e3 = edgeIds[st+j+3];
                    float v0 = bf2f(ea[(size_t)e0*HD + cg]);
                    float v1 = bf2f(ea[(size_t)e1*HD + cg]);
                    float v2 = bf2f(ea[(size_t)e2*HD + cg]);
                    float v3 = bf2f(ea[(size_t)e3*HD + cg]);
                    s += (v0 + v1) + (v2 + v3);
                }
                for (; j < dg; ++j)
                    s += bf2f(ea[(size_t)edgeIds[st+j]*HD + cg]);
                s *= invcnt[gn];
            }
            As[ln*NP + 128 + cg] = (short)f2bf(s);
        }
    }
    __syncthreads();

    // ---- phase 1: (32x256)@(256x256) ----
    f32x4 acc[2][4];
    #pragma unroll
    for (int rt=0;rt<2;++rt)
        #pragma unroll
        for (int c=0;c<4;++c) acc[rt][c] = (f32x4){0.f,0.f,0.f,0.f};

    #pragma unroll 2
    for (int kc = 0; kc < 8; ++kc){
        int k0 = kc*32 + lg*8;
        bf16x8 a0 = *(const bf16x8*)&As[(l15     )*NP + k0];
        bf16x8 a1 = *(const bf16x8*)&As[(l15 + 16)*NP + k0];
        #pragma unroll
        for (int c=0;c<4;++c){
            int colg = w*64 + c*16 + l15;
            bf16x8 b = *(const bf16x8*)&W1T[(size_t)colg*256 + k0];
            acc[0][c] = __builtin_amdgcn_mfma_f32_16x16x32_bf16(a0, b, acc[0][c], 0, 0, 0);
            acc[1][c] = __builtin_amdgcn_mfma_f32_16x16x32_bf16(a1, b, acc[1][c], 0, 0, 0);
        }
    }

    // ---- epilogue 1: +b1, LN(256), GELU -> A2s ----
    float b1c[4], g1c[4], t1c[4];
    #pragma unroll
    for (int c=0;c<4;++c){
        int colg = w*64 + c*16 + l15;
        b1c[c] = b1[colg]; g1c[c] = g1[colg]; t1c[c] = bt1[colg];
    }
    float xv[2][4][4];
    #pragma unroll
    for (int rt=0;rt<2;++rt)
        #pragma unroll
        for (int c=0;c<4;++c)
            #pragma unroll
            for (int i=0;i<4;++i) xv[rt][c][i] = acc[rt][c][i] + b1c[c];

    #pragma unroll
    for (int rt=0;rt<2;++rt)
        #pragma unroll
        for (int i=0;i<4;++i){
            float s=0.f, q=0.f;
            #pragma unroll
            for (int c=0;c<4;++c){ float v=xv[rt][c][i]; s+=v; q+=v*v; }
            #pragma unroll
            for (int m=1;m<16;m<<=1){ s += __shfl_xor(s,m); q += __shfl_xor(q,m); }
            if (l15 == 0){
                int r = rt*16 + lg*4 + i;
                red[w][r][0] = s;
                red[w][r][1] = q;
            }
        }
    __syncthreads();

    short* A2s = &As[0];
    #pragma unroll
    for (int rt=0;rt<2;++rt)
        #pragma unroll
        for (int i=0;i<4;++i){
            int r = rt*16 + lg*4 + i;
            float S = red[0][r][0]+red[1][r][0]+red[2][r][0]+red[3][r][0];
            float Q = red[0][r][1]+red[1][r][1]+red[2][r][1]+red[3][r][1];
            float mean = S * (1.f/256.f);
            float var  = Q * (1.f/256.f) - mean*mean;
            float rs = rsqrtf(var + LN_EPS);
            #pragma unroll
            for (int c=0;c<4;++c){
                int colg = w*64 + c*16 + l15;
                float v = (xv[rt][c][i]-mean)*rs*g1c[c] + t1c[c];
                A2s[r*NP + colg] = (short)f2bf(gelu_f(v));
            }
        }
    __syncthreads();

    // ---- phase 2: (32x256)@(256x128) ----
    f32x4 acc2[2][2];
    #pragma unroll
    for (int rt=0;rt<2;++rt)
        #pragma unroll
        for (int c=0;c<2;++c) acc2[rt][c] = (f32x4){0.f,0.f,0.f,0.f};

    #pragma unroll 2
    for (int kc = 0; kc < 8; ++kc){
        int k0 = kc*32 + lg*8;
        bf16x8 a0 = *(const bf16x8*)&A2s[(l15     )*NP + k0];
        bf16x8 a1 = *(const bf16x8*)&A2s[(l15 + 16)*NP + k0];
        #pragma unroll
        for (int c=0;c<2;++c){
            int colg = w*32 + c*16 + l15;
            bf16x8 b = *(const bf16x8*)&W2T[(size_t)colg*256 + k0];
            acc2[0][c] = __builtin_amdgcn_mfma_f32_16x16x32_bf16(a0, b, acc2[0][c], 0, 0, 0);
            acc2[1][c] = __builtin_amdgcn_mfma_f32_16x16x32_bf16(a1, b, acc2[1][c], 0, 0, 0);
        }
    }

    // ---- epilogue 2: +b2, LN(128), residual -> h + h_bf ----
    float b2c[2], g2c[2], t2c[2];
    #pragma unroll
    for (int c=0;c<2;++c){
        int colg = w*32 + c*16 + l15;
        b2c[c] = b2[colg]; g2c[c] = g2[colg]; t2c[c] = bt2[colg];
    }
    float yv[2][2][4];
    #pragma unroll
    for (int rt=0;rt<2;++rt)
        #pragma unroll
        for (int c=0;c<2;++c)
            #pragma unroll
            for (int i=0;i<4;++i) yv[rt][c][i] = acc2[rt][c][i] + b2c[c];

    __syncthreads();
    #pragma unroll
    for (int rt=0;rt<2;++rt)
        #pragma unroll
        for (int i=0;i<4;++i){
            float s=0.f, q=0.f;
            #pragma unroll
            for (int c=0;c<2;++c){ float v=yv[rt][c][i]; s+=v; q+=v*v; }
            #pragma unroll
            for (int m=1;m<16;m<<=1){ s += __shfl_xor(s,m); q += __shfl_xor(q,m); }
            if (l15 == 0){
                int r = rt*16 + lg*4 + i;
                red[w][r][0] = s;
                red[w][r][1] = q;
            }
        }
    __syncthreads();

    #pragma unroll
    for (int rt=0;rt<2;++rt)
        #pragma unroll
        for (int i=0;i<4;++i){
            int r = rt*16 + lg*4 + i;
            int gn = nBase + r;
            if (gn < NN){
                float S = red[0][r][0]+red[1][r][0]+red[2][r][0]+red[3][r][0];
                float Q = red[0][r][1]+red[1][r][1]+red[2][r][1]+red[3][r][1];
                float mean = S * (1.f/128.f);
                float var  = Q * (1.f/128.f) - mean*mean;
                float rs = rsqrtf(var + LN_EPS);
                size_t gbase = (size_t)gn*HD;
                #pragma unroll
                for (int c=0;c<2;++c){
                    int colg = w*32 + c*16 + l15;
                    float v = (yv[rt][c][i]-mean)*rs*g2c[c] + t2c[c];
                    float nv = h[gbase + colg] + v;
                    h[gbase + colg] = nv;
                    h_bf[gbase + colg] = f2bf(nv);
                }
            }
        }
}

// ---------------- decoder ----------------
__global__ __launch_bounds__(128) void k_decode(
    const float* __restrict__ h, const float* __restrict__ W1,
    const float* __restrict__ b1, const float* __restrict__ W2,
    const float* __restrict__ b2, float* __restrict__ out)
{
    int n = blockIdx.x, t = threadIdx.x;
    __shared__ float hs[128];
    __shared__ float red[8];
    hs[t] = h[(size_t)n*HD + t];
    __syncthreads();
    float o = b1[t];
    #pragma unroll 8
    for (int k = 0; k < 128; ++k) o += hs[k] * W1[k*128 + t];
    o = gelu_f(o);
    float p0 = o*W2[t*4+0], p1 = o*W2[t*4+1], p2 = o*W2[t*4+2], p3 = o*W2[t*4+3];
    #pragma unroll
    for (int m = 32; m >= 1; m >>= 1){
        p0 += __shfl_xor(p0, m); p1 += __shfl_xor(p1, m);
        p2 += __shfl_xor(p2, m); p3 += __shfl_xor(p3, m);
    }
    int wave = t >> 6;
    if ((t & 63) == 0){ red[wave*4+0]=p0; red[wave*4+1]=p1; red[wave*4+2]=p2; red[wave*4+3]=p3; }
    __syncthreads();
    if (t < 4) out[(size_t)n*4 + t] = red[t] + red[4+t] + b2[t];
}

// ---------------- launch ----------------
extern "C" void kernel_launch(void* const* d_in, const int* in_sizes, int n_in,
                              void* d_out, int out_size, void* d_ws, size_t ws_size,
                              hipStream_t stream)
{
    const float* x      = (const float*)d_in[0];
    const int*   eidx   = (const int*)d_in[1];
    const float* eattr  = (const float*)d_in[2];
    const float* enc_W  = (const float*)d_in[3];
    const float* enc_b  = (const float*)d_in[4];
    const float* enc_g  = (const float*)d_in[5];
    const float* enc_bt = (const float*)d_in[6];
    const float* ee_W   = (const float*)d_in[7];
    const float* ee_b   = (const float*)d_in[8];
    const float* eW1    = (const float*)d_in[9];
    const float* eb1    = (const float*)d_in[10];
    const float* eg1    = (const float*)d_in[11];
    const float* ebt1   = (const float*)d_in[12];
    const float* eW2    = (const float*)d_in[13];
    const float* eb2    = (const float*)d_in[14];
    const float* eg2    = (const float*)d_in[15];
    const float* ebt2   = (const float*)d_in[16];
    const float* nW1    = (const float*)d_in[17];
    const float* nb1    = (const float*)d_in[18];
    const float* ng1    = (const float*)d_in[19];
    const float* nbt1   = (const float*)d_in[20];
    const float* nW2    = (const float*)d_in[21];
    const float* nb2    = (const float*)d_in[22];
    const float* ng2    = (const float*)d_in[23];
    const float* nbt2   = (const float*)d_in[24];
    const float* dec_W1 = (const float*)d_in[25];
    const float* dec_b1 = (const float*)d_in[26];
    const float* dec_W2 = (const float*)d_in[27];
    const float* dec_b2 = (const float*)d_in[28];

    const int* row = eidx;
    const int* col = eidx + NE;

    char* ws0 = (char*)d_ws;
    char* ws = ws0;
    auto alloc = [&](size_t bytes) -> char* {
        char* p = ws;
        ws += (bytes + 255) & ~(size_t)255;
        return p;
    };
    ushort_t* ea      = (ushort_t*)alloc((size_t)NE*HD*2);       // 153.6 MB
    float*    h       = (float*)   alloc((size_t)NN*HD*4);       // 25.6 MB
    ushort_t* h_bf    = (ushort_t*)alloc((size_t)NN*HD*2);       // 12.8 MB
    ushort_t* W1Tb    = (ushort_t*)alloc((size_t)NL*256*384*2);  // 1.97 MB
    ushort_t* W2Tb    = (ushort_t*)alloc((size_t)NL*128*256*2);  // 0.66 MB
    ushort_t* nW1Tb   = (ushort_t*)alloc((size_t)NL*256*256*2);  // 1.31 MB
    ushort_t* nW2Tb   = (ushort_t*)alloc((size_t)NL*128*256*2);  // 0.66 MB
    int*      cnt     = (int*)     alloc((size_t)NN*4);
    int*      rowSt   = (int*)     alloc((size_t)NN*4);
    int*      fill    = (int*)     alloc((size_t)NN*4);
    float*    invcnt  = (float*)   alloc((size_t)NN*4);
    int*      edgeIds = (int*)     alloc((size_t)NE*4);
    int*      bsum    = (int*)     alloc(256*4);
    int*      boff    = (int*)     alloc(256*4);

    size_t need = (size_t)(ws - ws0);
    if (ws_size < need){
        k_sentinel_out<<<(out_size+255)/256, 256, 0, stream>>>((float*)d_out, out_size, 3.0f);
        return;
    }

    hipMemsetAsync(cnt,  0, (size_t)NN*4, stream);
    hipMemsetAsync(fill, 0, (size_t)NN*4, stream);

    k_wt<<<(NL*384*256+255)/256, 256, 0, stream>>>(eW1, W1Tb, 384, 256);
    k_wt<<<(NL*256*128+255)/256, 256, 0, stream>>>(eW2, W2Tb, 256, 128);
    k_wt<<<(NL*256*256+255)/256, 256, 0, stream>>>(nW1, nW1Tb, 256, 256);
    k_wt<<<(NL*256*128+255)/256, 256, 0, stream>>>(nW2, nW2Tb, 256, 128);

    k_encode_nodes<<<NN, 128, 0, stream>>>(x, enc_W, enc_b, enc_g, enc_bt, h, h_bf);
    k_encode_edges<<<NE/2, 256, 0, stream>>>(eattr, ee_W, ee_b, ea);

    k_hist <<<(NE+255)/256, 256, 0, stream>>>(col, cnt);
    k_scan1<<<NBLK, 256, 0, stream>>>(cnt, bsum);
    k_scan2<<<1, 256, 0, stream>>>(bsum, boff);
    k_scan3<<<NBLK, 256, 0, stream>>>(cnt, boff, rowSt, invcnt);
    k_fill <<<(NE+255)/256, 256, 0, stream>>>(col, rowSt, fill, edgeIds);

    for (int l = 0; l < NL; ++l){
        k_edge_update<<<NE/EB, 256, 0, stream>>>(h_bf, ea, row, col,
            W1Tb + (size_t)l*256*384, eb1 + l*256, eg1 + l*256, ebt1 + l*256,
            W2Tb + (size_t)l*128*256, eb2 + l*128, eg2 + l*128, ebt2 + l*128);
        k_node_update<<<(NN+31)/32, 256, 0, stream>>>(h, h_bf, ea, rowSt, cnt, invcnt, edgeIds,
            nW1Tb + (size_t)l*256*256, nb1 + l*256, ng1 + l*256, nbt1 + l*256,
            nW2Tb + (size_t)l*128*256, nb2 + l*128, ng2 + l*128, nbt2 + l*128);
    }

    k_decode<<<NN, 128, 0, stream>>>(h, dec_W1, dec_b1, dec_W2, dec_b2, (float*)d_out);
}

// Round 14
// 6769.403 us; speedup vs baseline: 1.0223x; 1.0223x over previous
//
#include <hip/hip_runtime.h>
#include <math.h>

#define NN 50000
#define NE 600000
#define HD 128
#define NL 10
#define LN_EPS 1e-5f
#define SCAN_B 256
#define NBLK ((NN + SCAN_B - 1) / SCAN_B)   // 196

typedef unsigned short ushort_t;
typedef __attribute__((ext_vector_type(8))) short bf16x8;
typedef __attribute__((ext_vector_type(4))) float f32x4;

// fast GELU: x*sigmoid(1.5957691*(x+0.044715*x^3)); |err| vs erf-GELU ~1e-3
__device__ __forceinline__ float gelu_f(float x){
    float x2 = x*x;
    float z  = 1.5957691f*x + 0.07135481f*x2*x;
    float s  = 1.0f/(1.0f + __expf(-z));
    return x*s;
}
__device__ __forceinline__ float bf2f(ushort_t u){
    unsigned int x = ((unsigned int)u) << 16;
    float f; __builtin_memcpy(&f, &x, 4); return f;
}
__device__ __forceinline__ ushort_t f2bf(float f){
    unsigned int x; __builtin_memcpy(&x, &f, 4);
    unsigned int lsb = (x >> 16) & 1u;
    x += 0x7fffu + lsb;                 // round-to-nearest-even
    return (ushort_t)(x >> 16);
}

// ---------------- sentinel fill (ws-too-small diagnostic) ----------------
__global__ void k_sentinel_out(float* __restrict__ out, int n, float v){
    int i = blockIdx.x*256 + threadIdx.x;
    if (i < n) out[i] = v;
}

// ---------------- weight pre-transpose+convert: WT[l][n][k] = bf16(W[l][k][n]) ----------------
__global__ void k_wt(const float* __restrict__ W, ushort_t* __restrict__ WT, int K, int N){
    int idx = blockIdx.x*256 + threadIdx.x;
    if (idx >= NL*K*N) return;
    int l = idx / (K*N);
    int rem = idx - l*(K*N);
    int n = rem / K;
    int k = rem - n*K;
    WT[idx] = f2bf(W[(size_t)l*K*N + (size_t)k*N + n]);
}

// ---------------- encoder: h = gelu(LN(x @ W + b)); writes f32 + bf16 mirror ----------------
__global__ __launch_bounds__(128) void k_encode_nodes(
    const float* __restrict__ x, const float* __restrict__ W,
    const float* __restrict__ b, const float* __restrict__ g,
    const float* __restrict__ beta, float* __restrict__ h, ushort_t* __restrict__ h_bf)
{
    int n = blockIdx.x;
    int t = threadIdx.x;
    __shared__ float xs[7];
    __shared__ float red[4];
    if (t < 7) xs[t] = x[n*7 + t];
    __syncthreads();
    float acc = b[t];
    #pragma unroll
    for (int i = 0; i < 7; ++i) acc += xs[i] * W[i*HD + t];
    float s = acc, s2 = acc*acc;
    #pragma unroll
    for (int m = 32; m >= 1; m >>= 1) { s += __shfl_xor(s, m); s2 += __shfl_xor(s2, m); }
    int wave = t >> 6;
    if ((t & 63) == 0) { red[wave*2] = s; red[wave*2+1] = s2; }
    __syncthreads();
    s = red[0] + red[2]; s2 = red[1] + red[3];
    float mean = s * (1.0f/HD);
    float var  = s2 * (1.0f/HD) - mean*mean;
    float rs = rsqrtf(var + LN_EPS);
    float v = (acc - mean) * rs * g[t] + beta[t];
    float o = gelu_f(v);
    h[(size_t)n*HD + t] = o;
    h_bf[(size_t)n*HD + t] = f2bf(o);
}

// ---------------- edge encoder: ea = attr @ W + b (bf16 store) ----------------
__global__ __launch_bounds__(256) void k_encode_edges(
    const float* __restrict__ attr, const float* __restrict__ W,
    const float* __restrict__ b, ushort_t* __restrict__ ea)
{
    int e = blockIdx.x * 2 + (threadIdx.x >> 7);
    int c = threadIdx.x & 127;
    float acc = b[c];
    #pragma unroll
    for (int i = 0; i < 8; ++i) acc += attr[(size_t)e*8 + i] * W[i*HD + c];
    ea[(size_t)e*HD + c] = f2bf(acc);
}

// ---------------- CSR build ----------------
__global__ void k_hist(const int* __restrict__ col, int* __restrict__ cnt){
    int e = blockIdx.x*256 + threadIdx.x;
    if (e < NE) atomicAdd(&cnt[col[e]], 1);
}

__global__ __launch_bounds__(256) void k_scan1(const int* __restrict__ cnt, int* __restrict__ bsum){
    __shared__ int s[256];
    int i = blockIdx.x*256 + threadIdx.x;
    int t = threadIdx.x;
    s[t] = (i < NN) ? cnt[i] : 0;
    __syncthreads();
    for (int off = 128; off >= 1; off >>= 1){
        if (t < off) s[t] += s[t+off];
        __syncthreads();
    }
    if (t == 0) bsum[blockIdx.x] = s[0];
}

__global__ __launch_bounds__(256) void k_scan2(const int* __restrict__ bsum, int* __restrict__ boff){
    __shared__ int s[256];
    int t = threadIdx.x;
    int v = (t < NBLK) ? bsum[t] : 0;
    s[t] = v; __syncthreads();
    for (int off = 1; off < 256; off <<= 1){
        int tmp = (t >= off) ? s[t-off] : 0;
        __syncthreads();
        s[t] += tmp;
        __syncthreads();
    }
    if (t < NBLK) boff[t] = s[t] - v;   // exclusive
}

__global__ __launch_bounds__(256) void k_scan3(const int* __restrict__ cnt, const int* __restrict__ boff,
        int* __restrict__ rowStart, float* __restrict__ invcnt){
    __shared__ int s[256];
    int i = blockIdx.x*256 + threadIdx.x;
    int t = threadIdx.x;
    int v = (i < NN) ? cnt[i] : 0;
    s[t] = v; __syncthreads();
    for (int off = 1; off < 256; off <<= 1){
        int tmp = (t >= off) ? s[t-off] : 0;
        __syncthreads();
        s[t] += tmp;
        __syncthreads();
    }
    if (i < NN){
        rowStart[i] = boff[blockIdx.x] + s[t] - v;
        invcnt[i]   = 1.0f / fmaxf((float)v, 1.0f);
    }
}

__global__ void k_fill(const int* __restrict__ col, const int* __restrict__ rowStart,
                       int* __restrict__ fill, int* __restrict__ edgeIds){
    int e = blockIdx.x*256 + threadIdx.x;
    if (e < NE){
        int c = col[e];
        int p = rowStart[c] + atomicAdd(&fill[c], 1);
        edgeIds[p] = e;
    }
}

// ---------------- MFMA fused edge update (64 edges/block, 4 waves, B reg-pipelined) ----------------
// Fragment maps: A: row=lane&15 (+16*rt), k=(lane>>4)*8+j.  B: col=lane&15, k=(lane>>4)*8+j.
// C/D: col=lane&15, row=(lane>>4)*4+reg (HW-verified).
#define EB 64    // edges per block
#define AP 392   // A LDS row stride (shorts)
#define A2P 264  // A2 row stride (shorts)
__global__ __launch_bounds__(256, 3) void k_edge_update(
    const ushort_t* __restrict__ h_bf, ushort_t* __restrict__ ea,
    const int* __restrict__ row, const int* __restrict__ col,
    const ushort_t* __restrict__ W1T, const float* __restrict__ b1,
    const float* __restrict__ g1, const float* __restrict__ bt1,
    const ushort_t* __restrict__ W2T, const float* __restrict__ b2,
    const float* __restrict__ g2, const float* __restrict__ bt2)
{
    __shared__ short As[EB*AP];          // 50176 B; aliased as A2s after phase 1
    __shared__ float red[4][EB][2];      // 2 KB cross-wave LN partials

    const int tid  = threadIdx.x;
    const int lane = tid & 63;
    const int w    = tid >> 6;           // wave 0..3
    const int l15  = lane & 15;
    const int lg   = lane >> 4;          // 0..3
    const int eBase = blockIdx.x * EB;

    // ---- B phase-1 prefetch ring (depth 4): issued FIRST so L2 latency hides under staging ----
    bf16x8 bf[4][4];
    #pragma unroll
    for (int p = 0; p < 4; ++p)
        #pragma unroll
        for (int c = 0; c < 4; ++c)
            bf[p][c] = *(const bf16x8*)&W1T[(size_t)(w*64 + c*16 + l15)*384 + p*32 + lg*8];

    // ---- stage A tile: raw bf16 uint4 copies (64 edges x 16 uint4 per segment) ----
    #pragma unroll
    for (int it = 0; it < 4; ++it){
        int f = tid + it*256;            // 0..1023
        int e = f >> 4, q = f & 15;
        int rn = row[eBase + e];         // 16 threads share e -> broadcast load
        uint4 v = *(const uint4*)(h_bf + (size_t)rn*HD + q*8);
        *(uint4*)&As[e*AP + q*8] = v;
    }
    #pragma unroll
    for (int it = 0; it < 4; ++it){
        int f = tid + it*256;
        int e = f >> 4, q = f & 15;
        int cn = col[eBase + e];
        uint4 v = *(const uint4*)(h_bf + (size_t)cn*HD + q*8);
        *(uint4*)&As[e*AP + 128 + q*8] = v;
    }
    #pragma unroll
    for (int it = 0; it < 4; ++it){
        int f = tid + it*256;
        int e = f >> 4, q = f & 15;
        uint4 v = *(const uint4*)(ea + (size_t)(eBase+e)*HD + q*8);
        *(uint4*)&As[e*AP + 256 + q*8] = v;
    }
    __syncthreads();

    // ---- phase 1: (64x384)@(384x256); B prefetched 4 deep ----
    f32x4 acc[4][4];
    #pragma unroll
    for (int rt=0;rt<4;++rt)
        #pragma unroll
        for (int c=0;c<4;++c) acc[rt][c] = (f32x4){0.f,0.f,0.f,0.f};

    #pragma unroll
    for (int kc = 0; kc < 12; ++kc){
        int k0 = kc*32 + lg*8;
        bf16x8 a[4];
        #pragma unroll
        for (int rt=0;rt<4;++rt) a[rt] = *(const bf16x8*)&As[(l15 + 16*rt)*AP + k0];
        #pragma unroll
        for (int c=0;c<4;++c){
            #pragma unroll
            for (int rt=0;rt<4;++rt)
                acc[rt][c] = __builtin_amdgcn_mfma_f32_16x16x32_bf16(a[rt], bf[kc&3][c], acc[rt][c], 0, 0, 0);
        }
        if (kc < 8){
            #pragma unroll
            for (int c=0;c<4;++c)
                bf[kc&3][c] = *(const bf16x8*)&W1T[(size_t)(w*64 + c*16 + l15)*384 + (kc+4)*32 + lg*8];
        }
    }

    // ---- capture old-ea for epilogue 2 from LDS (before A2s overwrite; reads race-free pre-barrier) ----
    ushort_t eaold[4][4][2];
    #pragma unroll
    for (int rt=0;rt<4;++rt)
        #pragma unroll
        for (int i=0;i<4;++i){
            int r = rt*16 + lg*4 + i;
            #pragma unroll
            for (int c=0;c<2;++c)
                eaold[rt][i][c] = (ushort_t)As[r*AP + 256 + w*32 + c*16 + l15];
        }

    // ---- epilogue 1: +b1, LN(256), GELU -> A2s (bf16) ----
    float b1c[4], g1c[4], t1c[4];
    #pragma unroll
    for (int c=0;c<4;++c){
        int colg = w*64 + c*16 + l15;
        b1c[c] = b1[colg]; g1c[c] = g1[colg]; t1c[c] = bt1[colg];
    }
    float xv[4][4][4];
    #pragma unroll
    for (int rt=0;rt<4;++rt)
        #pragma unroll
        for (int c=0;c<4;++c)
            #pragma unroll
            for (int i=0;i<4;++i) xv[rt][c][i] = acc[rt][c][i] + b1c[c];

    #pragma unroll
    for (int rt=0;rt<4;++rt)
        #pragma unroll
        for (int i=0;i<4;++i){
            float s=0.f, q=0.f;
            #pragma unroll
            for (int c=0;c<4;++c){ float v=xv[rt][c][i]; s+=v; q+=v*v; }
            #pragma unroll
            for (int m=1;m<16;m<<=1){ s += __shfl_xor(s,m); q += __shfl_xor(q,m); }
            if (l15 == 0){
                int r = rt*16 + lg*4 + i;
                red[w][r][0] = s;
                red[w][r][1] = q;
            }
        }
    __syncthreads();   // red ready; all phase-1 + capture LDS reads done before A2s overwrite

    // ---- B phase-2 prefetch ring: issued here so latency hides under epilogue-1 VALU ----
    bf16x8 bf2[4][2];
    #pragma unroll
    for (int p = 0; p < 4; ++p)
        #pragma unroll
        for (int c = 0; c < 2; ++c)
            bf2[p][c] = *(const bf16x8*)&W2T[(size_t)(w*32 + c*16 + l15)*256 + p*32 + lg*8];

    short* A2s = &As[0];
    #pragma unroll
    for (int rt=0;rt<4;++rt)
        #pragma unroll
        for (int i=0;i<4;++i){
            int r = rt*16 + lg*4 + i;
            float S = red[0][r][0]+red[1][r][0]+red[2][r][0]+red[3][r][0];
            float Q = red[0][r][1]+red[1][r][1]+red[2][r][1]+red[3][r][1];
            float mean = S * (1.f/256.f);
            float var  = Q * (1.f/256.f) - mean*mean;
            float rs = rsqrtf(var + LN_EPS);
            #pragma unroll
            for (int c=0;c<4;++c){
                int colg = w*64 + c*16 + l15;
                float v = (xv[rt][c][i]-mean)*rs*g1c[c] + t1c[c];
                A2s[r*A2P + colg] = (short)f2bf(gelu_f(v));
            }
        }
    __syncthreads();

    // ---- phase 2: (64x256)@(256x128) ----
    f32x4 acc2[4][2];
    #pragma unroll
    for (int rt=0;rt<4;++rt)
        #pragma unroll
        for (int c=0;c<2;++c) acc2[rt][c] = (f32x4){0.f,0.f,0.f,0.f};

    #pragma unroll
    for (int kc = 0; kc < 8; ++kc){
        int k0 = kc*32 + lg*8;
        bf16x8 a[4];
        #pragma unroll
        for (int rt=0;rt<4;++rt) a[rt] = *(const bf16x8*)&A2s[(l15 + 16*rt)*A2P + k0];
        #pragma unroll
        for (int c=0;c<2;++c){
            #pragma unroll
            for (int rt=0;rt<4;++rt)
                acc2[rt][c] = __builtin_amdgcn_mfma_f32_16x16x32_bf16(a[rt], bf2[kc&3][c], acc2[rt][c], 0, 0, 0);
        }
        if (kc < 4){
            #pragma unroll
            for (int c=0;c<2;++c)
                bf2[kc&3][c] = *(const bf16x8*)&W2T[(size_t)(w*32 + c*16 + l15)*256 + (kc+4)*32 + lg*8];
        }
    }

    // ---- epilogue 2: +b2, LN(128), residual into ea (bf16; old value from captured regs) ----
    float b2c[2], g2c[2], t2c[2];
    #pragma unroll
    for (int c=0;c<2;++c){
        int colg = w*32 + c*16 + l15;
        b2c[c] = b2[colg]; g2c[c] = g2[colg]; t2c[c] = bt2[colg];
    }
    float yv[4][2][4];
    #pragma unroll
    for (int rt=0;rt<4;++rt)
        #pragma unroll
        for (int c=0;c<2;++c)
            #pragma unroll
            for (int i=0;i<4;++i) yv[rt][c][i] = acc2[rt][c][i] + b2c[c];

    __syncthreads();   // ensure epi-1 red reads done before reuse
    #pragma unroll
    for (int rt=0;rt<4;++rt)
        #pragma unroll
        for (int i=0;i<4;++i){
            float s=0.f, q=0.f;
            #pragma unroll
            for (int c=0;c<2;++c){ float v=yv[rt][c][i]; s+=v; q+=v*v; }
            #pragma unroll
            for (int m=1;m<16;m<<=1){ s += __shfl_xor(s,m); q += __shfl_xor(q,m); }
            if (l15 == 0){
                int r = rt*16 + lg*4 + i;
                red[w][r][0] = s;
                red[w][r][1] = q;
            }
        }
    __syncthreads();

    #pragma unroll
    for (int rt=0;rt<4;++rt)
        #pragma unroll
        for (int i=0;i<4;++i){
            int r = rt*16 + lg*4 + i;
            float S = red[0][r][0]+red[1][r][0]+red[2][r][0]+red[3][r][0];
            float Q = red[0][r][1]+red[1][r][1]+red[2][r][1]+red[3][r][1];
            float mean = S * (1.f/128.f);
            float var  = Q * (1.f/128.f) - mean*mean;
            float rs = rsqrtf(var + LN_EPS);
            size_t gbase = (size_t)(eBase + r)*HD;
            #pragma unroll
            for (int c=0;c<2;++c){
                int colg = w*32 + c*16 + l15;
                float v = (yv[rt][c][i]-mean)*rs*g2c[c] + t2c[c];
                float old = bf2f(eaold[rt][i][c]);
                ea[gbase + colg] = f2bf(old + v);
            }
        }
}

// ---------------- MFMA fused node update (agg fused in, gather unrolled x4) ----------------
#define NP 264   // LDS row stride (shorts) for 256-col tiles
__global__ __launch_bounds__(256) void k_node_update(
    float* __restrict__ h, ushort_t* __restrict__ h_bf,
    const ushort_t* __restrict__ ea,
    const int* __restrict__ rowSt, const int* __restrict__ cnt,
    const float* __restrict__ invcnt, const int* __restrict__ edgeIds,
    const ushort_t* __restrict__ W1T, const float* __restrict__ b1,
    const float* __restrict__ g1, const float* __restrict__ bt1,
    const ushort_t* __restrict__ W2T, const float* __restrict__ b2,
    const float* __restrict__ g2, const float* __restrict__ bt2)
{
    __shared__ short As[32*NP];          // 16896 B; reused as A2s after phase 1
    __shared__ float red[4][32][2];

    const int tid  = threadIdx.x;
    const int lane = tid & 63;
    const int w    = tid >> 6;
    const int l15  = lane & 15;
    const int lg   = lane >> 4;
    const int nBase = blockIdx.x * 32;

    // ---- stage h_bf rows (cols 0..127) ----
    #pragma unroll
    for (int it = 0; it < 2; ++it){
        int f = tid + it*256;            // 0..511
        int e = f >> 4, q = f & 15;
        int gn = nBase + e;
        uint4 v = make_uint4(0,0,0,0);
        if (gn < NN) v = *(const uint4*)(h_bf + (size_t)gn*HD + q*8);
        *(uint4*)&As[e*NP + q*8] = v;
    }
    // ---- CSR gather-mean into cols 128..255 (bf16), 4-way unrolled ----
    {
        const int cg  = tid & 127;
        const int grp = tid >> 7;
        for (int i = 0; i < 16; ++i){
            int ln = grp*16 + i;
            int gn = nBase + ln;
            float s = 0.f;
            if (gn < NN){
                int st = rowSt[gn], dg = cnt[gn];
                int j = 0;
                for (; j + 4 <= dg; j += 4){
                    int e0 = edgeIds[st+j+0];
                    int e1 = edgeIds[st+j+1];
                    int e2 = edgeIds[st+j+2];
                    int e3 = edgeIds[st+j+3];
                    float v0 = bf2f(ea[(size_t)e0*HD + cg]);
                    float v1 = bf2f(ea[(size_t)e1*HD + cg]);
                    float v2 = bf2f(ea[(size_t)e2*HD + cg]);
                    float v3 = bf2f(ea[(size_t)e3*HD + cg]);
                    s += (v0 + v1) + (v2 + v3);
                }
                for (; j < dg; ++j)
                    s += bf2f(ea[(size_t)edgeIds[st+j]*HD + cg]);
                s *= invcnt[gn];
            }
            As[ln*NP + 128 + cg] = (short)f2bf(s);
        }
    }
    __syncthreads();

    // ---- phase 1: (32x256)@(256x256) ----
    f32x4 acc[2][4];
    #pragma unroll
    for (int rt=0;rt<2;++rt)
        #pragma unroll
        for (int c=0;c<4;++c) acc[rt][c] = (f32x4){0.f,0.f,0.f,0.f};

    #pragma unroll 2
    for (int kc = 0; kc < 8; ++kc){
        int k0 = kc*32 + lg*8;
        bf16x8 a0 = *(const bf16x8*)&As[(l15     )*NP + k0];
        bf16x8 a1 = *(const bf16x8*)&As[(l15 + 16)*NP + k0];
        #pragma unroll
        for (int c=0;c<4;++c){
            int colg = w*64 + c*16 + l15;
            bf16x8 b = *(const bf16x8*)&W1T[(size_t)colg*256 + k0];
            acc[0][c] = __builtin_amdgcn_mfma_f32_16x16x32_bf16(a0, b, acc[0][c], 0, 0, 0);
            acc[1][c] = __builtin_amdgcn_mfma_f32_16x16x32_bf16(a1, b, acc[1][c], 0, 0, 0);
        }
    }

    // ---- epilogue 1: +b1, LN(256), GELU -> A2s ----
    float b1c[4], g1c[4], t1c[4];
    #pragma unroll
    for (int c=0;c<4;++c){
        int colg = w*64 + c*16 + l15;
        b1c[c] = b1[colg]; g1c[c] = g1[colg]; t1c[c] = bt1[colg];
    }
    float xv[2][4][4];
    #pragma unroll
    for (int rt=0;rt<2;++rt)
        #pragma unroll
        for (int c=0;c<4;++c)
            #pragma unroll
            for (int i=0;i<4;++i) xv[rt][c][i] = acc[rt][c][i] + b1c[c];

    #pragma unroll
    for (int rt=0;rt<2;++rt)
        #pragma unroll
        for (int i=0;i<4;++i){
            float s=0.f, q=0.f;
            #pragma unroll
            for (int c=0;c<4;++c){ float v=xv[rt][c][i]; s+=v; q+=v*v; }
            #pragma unroll
            for (int m=1;m<16;m<<=1){ s += __shfl_xor(s,m); q += __shfl_xor(q,m); }
            if (l15 == 0){
                int r = rt*16 + lg*4 + i;
                red[w][r][0] = s;
                red[w][r][1] = q;
            }
        }
    __syncthreads();

    short* A2s = &As[0];
    #pragma unroll
    for (int rt=0;rt<2;++rt)
        #pragma unroll
        for (int i=0;i<4;++i){
            int r = rt*16 + lg*4 + i;
            float S = red[0][r][0]+red[1][r][0]+red[2][r][0]+red[3][r][0];
            float Q = red[0][r][1]+red[1][r][1]+red[2][r][1]+red[3][r][1];
            float mean = S * (1.f/256.f);
            float var  = Q * (1.f/256.f) - mean*mean;
            float rs = rsqrtf(var + LN_EPS);
            #pragma unroll
            for (int c=0;c<4;++c){
                int colg = w*64 + c*16 + l15;
                float v = (xv[rt][c][i]-mean)*rs*g1c[c] + t1c[c];
                A2s[r*NP + colg] = (short)f2bf(gelu_f(v));
            }
        }
    __syncthreads();

    // ---- phase 2: (32x256)@(256x128) ----
    f32x4 acc2[2][2];
    #pragma unroll
    for (int rt=0;rt<2;++rt)
        #pragma unroll
        for (int c=0;c<2;++c) acc2[rt][c] = (f32x4){0.f,0.f,0.f,0.f};

    #pragma unroll 2
    for (int kc = 0; kc < 8; ++kc){
        int k0 = kc*32 + lg*8;
        bf16x8 a0 = *(const bf16x8*)&A2s[(l15     )*NP + k0];
        bf16x8 a1 = *(const bf16x8*)&A2s[(l15 + 16)*NP + k0];
        #pragma unroll
        for (int c=0;c<2;++c){
            int colg = w*32 + c*16 + l15;
            bf16x8 b = *(const bf16x8*)&W2T[(size_t)colg*256 + k0];
            acc2[0][c] = __builtin_amdgcn_mfma_f32_16x16x32_bf16(a0, b, acc2[0][c], 0, 0, 0);
            acc2[1][c] = __builtin_amdgcn_mfma_f32_16x16x32_bf16(a1, b, acc2[1][c], 0, 0, 0);
        }
    }

    // ---- epilogue 2: +b2, LN(128), residual -> h + h_bf ----
    float b2c[2], g2c[2], t2c[2];
    #pragma unroll
    for (int c=0;c<2;++c){
        int colg = w*32 + c*16 + l15;
        b2c[c] = b2[colg]; g2c[c] = g2[colg]; t2c[c] = bt2[colg];
    }
    float yv[2][2][4];
    #pragma unroll
    for (int rt=0;rt<2;++rt)
        #pragma unroll
        for (int c=0;c<2;++c)
            #pragma unroll
            for (int i=0;i<4;++i) yv[rt][c][i] = acc2[rt][c][i] + b2c[c];

    __syncthreads();
    #pragma unroll
    for (int rt=0;rt<2;++rt)
        #pragma unroll
        for (int i=0;i<4;++i){
            float s=0.f, q=0.f;
            #pragma unroll
            for (int c=0;c<2;++c){ float v=yv[rt][c][i]; s+=v; q+=v*v; }
            #pragma unroll
            for (int m=1;m<16;m<<=1){ s += __shfl_xor(s,m); q += __shfl_xor(q,m); }
            if (l15 == 0){
                int r = rt*16 + lg*4 + i;
                red[w][r][0] = s;
                red[w][r][1] = q;
            }
        }
    __syncthreads();

    #pragma unroll
    for (int rt=0;rt<2;++rt)
        #pragma unroll
        for (int i=0;i<4;++i){
            int r = rt*16 + lg*4 + i;
            int gn = nBase + r;
            if (gn < NN){
                float S = red[0][r][0]+red[1][r][0]+red[2][r][0]+red[3][r][0];
                float Q = red[0][r][1]+red[1][r][1]+red[2][r][1]+red[3][r][1];
                float mean = S * (1.f/128.f);
                float var  = Q * (1.f/128.f) - mean*mean;
                float rs = rsqrtf(var + LN_EPS);
                size_t gbase = (size_t)gn*HD;
                #pragma unroll
                for (int c=0;c<2;++c){
                    int colg = w*32 + c*16 + l15;
                    float v = (yv[rt][c][i]-mean)*rs*g2c[c] + t2c[c];
                    float nv = h[gbase + colg] + v;
                    h[gbase + colg] = nv;
                    h_bf[gbase + colg] = f2bf(nv);
                }
            }
        }
}

// ---------------- decoder ----------------
__global__ __launch_bounds__(128) void k_decode(
    const float* __restrict__ h, const float* __restrict__ W1,
    const float* __restrict__ b1, const float* __restrict__ W2,
    const float* __restrict__ b2, float* __restrict__ out)
{
    int n = blockIdx.x, t = threadIdx.x;
    __shared__ float hs[128];
    __shared__ float red[8];
    hs[t] = h[(size_t)n*HD + t];
    __syncthreads();
    float o = b1[t];
    #pragma unroll 8
    for (int k = 0; k < 128; ++k) o += hs[k] * W1[k*128 + t];
    o = gelu_f(o);
    float p0 = o*W2[t*4+0], p1 = o*W2[t*4+1], p2 = o*W2[t*4+2], p3 = o*W2[t*4+3];
    #pragma unroll
    for (int m = 32; m >= 1; m >>= 1){
        p0 += __shfl_xor(p0, m); p1 += __shfl_xor(p1, m);
        p2 += __shfl_xor(p2, m); p3 += __shfl_xor(p3, m);
    }
    int wave = t >> 6;
    if ((t & 63) == 0){ red[wave*4+0]=p0; red[wave*4+1]=p1; red[wave*4+2]=p2; red[wave*4+3]=p3; }
    __syncthreads();
    if (t < 4) out[(size_t)n*4 + t] = red[t] + red[4+t] + b2[t];
}

// ---------------- launch ----------------
extern "C" void kernel_launch(void* const* d_in, const int* in_sizes, int n_in,
                              void* d_out, int out_size, void* d_ws, size_t ws_size,
                              hipStream_t stream)
{
    const float* x      = (const float*)d_in[0];
    const int*   eidx   = (const int*)d_in[1];
    const float* eattr  = (const float*)d_in[2];
    const float* enc_W  = (const float*)d_in[3];
    const float* enc_b  = (const float*)d_in[4];
    const float* enc_g  = (const float*)d_in[5];
    const float* enc_bt = (const float*)d_in[6];
    const float* ee_W   = (const float*)d_in[7];
    const float* ee_b   = (const float*)d_in[8];
    const float* eW1    = (const float*)d_in[9];
    const float* eb1    = (const float*)d_in[10];
    const float* eg1    = (const float*)d_in[11];
    const float* ebt1   = (const float*)d_in[12];
    const float* eW2    = (const float*)d_in[13];
    const float* eb2    = (const float*)d_in[14];
    const float* eg2    = (const float*)d_in[15];
    const float* ebt2   = (const float*)d_in[16];
    const float* nW1    = (const float*)d_in[17];
    const float* nb1    = (const float*)d_in[18];
    const float* ng1    = (const float*)d_in[19];
    const float* nbt1   = (const float*)d_in[20];
    const float* nW2    = (const float*)d_in[21];
    const float* nb2    = (const float*)d_in[22];
    const float* ng2    = (const float*)d_in[23];
    const float* nbt2   = (const float*)d_in[24];
    const float* dec_W1 = (const float*)d_in[25];
    const float* dec_b1 = (const float*)d_in[26];
    const float* dec_W2 = (const float*)d_in[27];
    const float* dec_b2 = (const float*)d_in[28];

    const int* row = eidx;
    const int* col = eidx + NE;

    char* ws0 = (char*)d_ws;
    char* ws = ws0;
    auto alloc = [&](size_t bytes) -> char* {
        char* p = ws;
        ws += (bytes + 255) & ~(size_t)255;
        return p;
    };
    ushort_t* ea      = (ushort_t*)alloc((size_t)NE*HD*2);       // 153.6 MB
    float*    h       = (float*)   alloc((size_t)NN*HD*4);       // 25.6 MB
    ushort_t* h_bf    = (ushort_t*)alloc((size_t)NN*HD*2);       // 12.8 MB
    ushort_t* W1Tb    = (ushort_t*)alloc((size_t)NL*256*384*2);  // 1.97 MB
    ushort_t* W2Tb    = (ushort_t*)alloc((size_t)NL*128*256*2);  // 0.66 MB
    ushort_t* nW1Tb   = (ushort_t*)alloc((size_t)NL*256*256*2);  // 1.31 MB
    ushort_t* nW2Tb   = (ushort_t*)alloc((size_t)NL*128*256*2);  // 0.66 MB
    int*      cnt     = (int*)     alloc((size_t)NN*4);
    int*      rowSt   = (int*)     alloc((size_t)NN*4);
    int*      fill    = (int*)     alloc((size_t)NN*4);
    float*    invcnt  = (float*)   alloc((size_t)NN*4);
    int*      edgeIds = (int*)     alloc((size_t)NE*4);
    int*      bsum    = (int*)     alloc(256*4);
    int*      boff    = (int*)     alloc(256*4);

    size_t need = (size_t)(ws - ws0);
    if (ws_size < need){
        k_sentinel_out<<<(out_size+255)/256, 256, 0, stream>>>((float*)d_out, out_size, 3.0f);
        return;
    }

    hipMemsetAsync(cnt,  0, (size_t)NN*4, stream);
    hipMemsetAsync(fill, 0, (size_t)NN*4, stream);

    k_wt<<<(NL*384*256+255)/256, 256, 0, stream>>>(eW1, W1Tb, 384, 256);
    k_wt<<<(NL*256*128+255)/256, 256, 0, stream>>>(eW2, W2Tb, 256, 128);
    k_wt<<<(NL*256*256+255)/256, 256, 0, stream>>>(nW1, nW1Tb, 256, 256);
    k_wt<<<(NL*256*128+255)/256, 256, 0, stream>>>(nW2, nW2Tb, 256, 128);

    k_encode_nodes<<<NN, 128, 0, stream>>>(x, enc_W, enc_b, enc_g, enc_bt, h, h_bf);
    k_encode_edges<<<NE/2, 256, 0, stream>>>(eattr, ee_W, ee_b, ea);

    k_hist <<<(NE+255)/256, 256, 0, stream>>>(col, cnt);
    k_scan1<<<NBLK, 256, 0, stream>>>(cnt, bsum);
    k_scan2<<<1, 256, 0, stream>>>(bsum, boff);
    k_scan3<<<NBLK, 256, 0, stream>>>(cnt, boff, rowSt, invcnt);
    k_fill <<<(NE+255)/256, 256, 0, stream>>>(col, rowSt, fill, edgeIds);

    for (int l = 0; l < NL; ++l){
        k_edge_update<<<NE/EB, 256, 0, stream>>>(h_bf, ea, row, col,
            W1Tb + (size_t)l*256*384, eb1 + l*256, eg1 + l*256, ebt1 + l*256,
            W2Tb + (size_t)l*128*256, eb2 + l*128, eg2 + l*128, ebt2 + l*128);
        k_node_update<<<(NN+31)/32, 256, 0, stream>>>(h, h_bf, ea, rowSt, cnt, invcnt, edgeIds,
            nW1Tb + (size_t)l*256*256, nb1 + l*256, ng1 + l*256, nbt1 + l*256,
            nW2Tb + (size_t)l*128*256, nb2 + l*128, ng2 + l*128, nbt2 + l*128);
    }

    k_decode<<<NN, 128, 0, stream>>>(h, dec_W1, dec_b1, dec_W2, dec_b2, (float*)d_out);
}